// Round 1
// baseline (977.373 us; speedup 1.0000x reference)
//
#include <hip/hip_runtime.h>
#include <math.h>

// Problem dims
constexpr int K_ = 128, J_ = 4, R_ = 32, T_ = 32, S_ = 256, A_ = 4, D_ = 64;
constexpr int Z_ = K_ * J_;
constexpr int NDF_ = 128;          // 2N
constexpr float RATE_ = 10.0f;     // 1/PRIOR_BL

// Output offsets (float elements) in return order
constexpr int OFF_M1   = 0;                       // K x 33 (int->float)
constexpr int OFF_M2   = OFF_M1 + K_ * 33;        // 4224
constexpr int OFF_B1   = OFF_M2 + K_ * 33;        // 8448
constexpr int OFF_B2   = OFF_B1 + K_ * 33;        // 12672
constexpr int OFF_EMBR = OFF_B2 + K_ * 33;        // 16896, K x 33 x 64
constexpr int OFF_LC   = OFF_EMBR + K_ * 33 * D_; // 287232, K x 31
constexpr int OFF_H    = OFF_LC + K_ * 31;        // 291200
constexpr int OFF_EMBT = OFF_H + K_ * 31;         // 295168, K x 31 x 64
constexpr int OFF_LF   = OFF_EMBT + K_ * 31 * D_; // 549120, K x 31 x 256 x 4
constexpr int OFF_LPN  = OFF_LF + K_ * 31 * S_ * A_; // 4612352
constexpr int OFF_LW   = OFF_LPN + K_;            // 4612480
constexpr int OFF_LL   = OFF_LW + K_;             // 4612608

// ---------- device helpers ----------

__device__ inline float lse4f(float a, float b, float c, float d) {
    float m = fmaxf(fmaxf(a, b), fmaxf(c, d));
    return m + logf(expf(a - m) + expf(b - m) + expf(c - m) + expf(d - m));
}

// 4x4 matrix exponential, double precision, scaling-and-squaring + Taylor(12)
__device__ void expm4(const double* M, double* E) {
    double norm = 0.0;
    for (int i = 0; i < 4; ++i) {
        double r = 0.0;
        for (int j = 0; j < 4; ++j) r += fabs(M[i * 4 + j]);
        norm = fmax(norm, r);
    }
    int s = 0;
    double scale = 1.0;
    while (norm > 0.25 && s < 30) { norm *= 0.5; scale *= 0.5; ++s; }
    double Asc[16], term[16], acc[16];
    for (int i = 0; i < 16; ++i) Asc[i] = M[i] * scale;
    for (int i = 0; i < 16; ++i) { term[i] = (i % 5 == 0) ? 1.0 : 0.0; acc[i] = term[i]; }
    for (int n = 1; n <= 12; ++n) {
        double tmp[16];
        for (int i = 0; i < 4; ++i)
            for (int j = 0; j < 4; ++j) {
                double v = 0.0;
                for (int l = 0; l < 4; ++l) v += term[i * 4 + l] * Asc[l * 4 + j];
                tmp[i * 4 + j] = v / (double)n;
            }
        for (int i = 0; i < 16; ++i) { term[i] = tmp[i]; acc[i] += tmp[i]; }
    }
    for (int q = 0; q < s; ++q) {
        double tmp[16];
        for (int i = 0; i < 4; ++i)
            for (int j = 0; j < 4; ++j) {
                double v = 0.0;
                for (int l = 0; l < 4; ++l) v += acc[i * 4 + l] * acc[l * 4 + j];
                tmp[i * 4 + j] = v;
            }
        for (int i = 0; i < 16; ++i) acc[i] = tmp[i];
    }
    for (int i = 0; i < 16; ++i) E[i] = acc[i];
}

// single-thread: Q from emb@Wq (f32 logits, softplus), then logP1/logP2
__device__ void compute_logP_pair(const float* __restrict__ emb,
                                  const float* __restrict__ Wq,
                                  float br1, float br2,
                                  float* logP1, float* logP2) {
    double Qm[16];
    for (int a = 0; a < 4; ++a) {
        double rs = 0.0;
        for (int b = 0; b < 4; ++b) {
            int p = a * 4 + b;
            float lg = 0.f;
            for (int d = 0; d < D_; ++d) lg += emb[d] * Wq[d * 16 + p];
            if (b != a) {
                double x = (double)lg;
                double sp = (x > 30.0) ? x : log1p(exp(x));
                Qm[p] = sp;
                rs += sp;
            }
        }
        Qm[a * 4 + a] = -rs;
    }
    double M[16], P[16];
    for (int i = 0; i < 16; ++i) M[i] = Qm[i] * (double)br1;
    expm4(M, P);
    for (int i = 0; i < 16; ++i) {
        double p = P[i]; if (p < 1e-30) p = 1e-30;
        logP1[i] = (float)log(p);
    }
    for (int i = 0; i < 16; ++i) M[i] = Qm[i] * (double)br2;
    expm4(M, P);
    for (int i = 0; i < 16; ++i) {
        double p = P[i]; if (p < 1e-30) p = 1e-30;
        logP2[i] = (float)log(p);
    }
}

// ---------- kernel 1: node_ll[k][t] = sum_s LSE_a(lf + log_stat_orig) ----------
__global__ __launch_bounds__(256) void k_node_ll(
    const int* __restrict__ indexes, const float* __restrict__ embt,
    const float* __restrict__ Wstat, const float* __restrict__ lf,
    float* __restrict__ node_ll) {
    int kt = blockIdx.x;
    int k = kt / T_, t = kt % T_;
    int src = indexes[k];
    int tid = threadIdx.x, wave = tid >> 6, lane = tid & 63;
    __shared__ float s_logit[4];
    __shared__ double s_part[4];
    // stat logits: wave w computes a=w via 64-lane dot over D
    {
        float e = embt[(src * T_ + t) * D_ + lane];
        float v = e * Wstat[lane * A_ + wave];
        for (int o = 32; o > 0; o >>= 1) v += __shfl_down(v, o, 64);
        if (lane == 0) s_logit[wave] = v;
    }
    __syncthreads();
    float l0 = s_logit[0], l1 = s_logit[1], l2 = s_logit[2], l3 = s_logit[3];
    float lse = lse4f(l0, l1, l2, l3);
    float ls0 = l0 - lse, ls1 = l1 - lse, ls2 = l2 - lse, ls3 = l3 - lse;
    // one site per thread
    const float4 f = *(const float4*)&lf[((size_t)(src * T_ + t) * S_ + tid) * A_];
    float site = lse4f(f.x + ls0, f.y + ls1, f.z + ls2, f.w + ls3);
    double v = (double)site;
    for (int o = 32; o > 0; o >>= 1) v += __shfl_down(v, o, 64);
    if (lane == 0) s_part[wave] = v;
    __syncthreads();
    if (tid == 0)
        node_ll[k * T_ + t] = (float)(s_part[0] + s_part[1] + s_part[2] + s_part[3]);
}

// ---------- kernel 2: per-proposal new-node log-lik ----------
__global__ __launch_bounds__(256) void k_hyp(
    const int* __restrict__ indexes, const int* __restrict__ idx1_KJ,
    const int* __restrict__ idx2_KJ, const float* __restrict__ br1_KJ,
    const float* __restrict__ br2_KJ, const float* __restrict__ emb_KJD,
    const float* __restrict__ Wq, const float* __restrict__ Wstat,
    const float* __restrict__ lf, float* __restrict__ new_node_ll) {
    int z = blockIdx.x;
    int k = z / J_;
    int src = indexes[k];
    int i1 = idx1_KJ[z], i2 = idx2_KJ[z];
    int tid = threadIdx.x, wave = tid >> 6, lane = tid & 63;
    __shared__ float s_logP1[16], s_logP2[16], s_logit[4];
    __shared__ double s_part[4];
    // stat logits for the NEW node (emb_z @ Wstat)
    {
        float e = emb_KJD[z * D_ + lane];
        float v = e * Wstat[lane * A_ + wave];
        for (int o = 32; o > 0; o >>= 1) v += __shfl_down(v, o, 64);
        if (lane == 0) s_logit[wave] = v;
    }
    if (tid == 0)
        compute_logP_pair(&emb_KJD[z * D_], Wq, br1_KJ[z], br2_KJ[z], s_logP1, s_logP2);
    __syncthreads();
    float l0 = s_logit[0], l1 = s_logit[1], l2 = s_logit[2], l3 = s_logit[3];
    float lse = lse4f(l0, l1, l2, l3);
    float ls[4] = {l0 - lse, l1 - lse, l2 - lse, l3 - lse};
    const float4 f1 = *(const float4*)&lf[((size_t)(src * T_ + i1) * S_ + tid) * A_];
    const float4 f2 = *(const float4*)&lf[((size_t)(src * T_ + i2) * S_ + tid) * A_];
    float nlf[4];
#pragma unroll
    for (int a = 0; a < 4; ++a) {
        float t1 = lse4f(s_logP1[a * 4 + 0] + f1.x, s_logP1[a * 4 + 1] + f1.y,
                         s_logP1[a * 4 + 2] + f1.z, s_logP1[a * 4 + 3] + f1.w);
        float t2 = lse4f(s_logP2[a * 4 + 0] + f2.x, s_logP2[a * 4 + 1] + f2.y,
                         s_logP2[a * 4 + 2] + f2.z, s_logP2[a * 4 + 3] + f2.w);
        nlf[a] = t1 + t2;
    }
    float site = lse4f(nlf[0] + ls[0], nlf[1] + ls[1], nlf[2] + ls[2], nlf[3] + ls[3]);
    double v = (double)site;
    for (int o = 32; o > 0; o >>= 1) v += __shfl_down(v, o, 64);
    if (lane == 0) s_part[wave] = v;
    __syncthreads();
    if (tid == 0)
        new_node_ll[z] = (float)(s_part[0] + s_part[1] + s_part[2] + s_part[3]);
}

// ---------- kernel 3: weights, selection, scalar outputs ----------
__global__ __launch_bounds__(64) void k_finalize(
    const int* __restrict__ indexes, const int* __restrict__ lc_Kt,
    const float* __restrict__ b1_Kr, const float* __restrict__ b2_Kr,
    const float* __restrict__ logpi_K, const int* __restrict__ idx1_KJ,
    const int* __restrict__ idx2_KJ, const float* __restrict__ br1_KJ,
    const float* __restrict__ br2_KJ, const float* __restrict__ logvp_KJ,
    const float* __restrict__ gumbel_KJ, const float* __restrict__ ldf,
    const float* __restrict__ node_ll, const float* __restrict__ new_node_ll,
    float* __restrict__ out, int* __restrict__ sub_idx) {
    int k = blockIdx.x;
    int lane = threadIdx.x;
    int src = indexes[k];
    double nll = 0.0, topo = 0.0, sb1 = 0.0, sb2 = 0.0;
    int cnt = 0;
    if (lane < T_) {
        nll = (double)node_ll[k * T_ + lane];
        int lc = lc_Kt[src * T_ + lane];
        int di = 2 * lc - 3; di = max(0, min(NDF_ - 1, di));
        topo = (double)ldf[di];
        cnt = (lc > 1) ? 1 : 0;
        sb1 = (double)b1_Kr[src * R_ + lane];  // R_ == T_ == 32
        sb2 = (double)b2_Kr[src * R_ + lane];
    }
    for (int o = 32; o > 0; o >>= 1) {
        nll += __shfl_down(nll, o, 64);
        topo += __shfl_down(topo, o, 64);
        sb1 += __shfl_down(sb1, o, 64);
        sb2 += __shfl_down(sb2, o, 64);
        cnt += __shfl_down(cnt, o, 64);
    }
    if (lane == 0) {
        double total_ll = nll, base_topo = -topo;
        const double lr = log(10.0);
        double lw[4], lpn[4], llik[4];
        for (int j = 0; j < J_; ++j) {
            int z = k * J_ + j;
            int i1 = idx1_KJ[z], i2 = idx2_KJ[z];
            int lc1 = lc_Kt[src * T_ + i1], lc2 = lc_Kt[src * T_ + i2];
            int nlc = lc1 + lc2;
            double loglik = total_ll - (double)node_ll[k * T_ + i1]
                                     - (double)node_ll[k * T_ + i2]
                                     + (double)new_node_ll[z];
            double lbp = 66.0 * lr
                       - (double)RATE_ * (sb1 + (double)br1_KJ[z] + sb2 + (double)br2_KJ[z]);
            int d1 = max(0, min(NDF_ - 1, 2 * lc1 - 3));
            int d2 = max(0, min(NDF_ - 1, 2 * lc2 - 3));
            int dn = max(0, min(NDF_ - 1, 2 * nlc - 3));
            double lt = base_topo + (double)ldf[d1] + (double)ldf[d2] - (double)ldf[dn];
            int cntj = cnt - ((lc1 > 1) ? 1 : 0) - ((lc2 > 1) ? 1 : 0) + 1;
            double lvm = log((double)cntj);
            lpn[j] = loglik + lbp + lt;
            llik[j] = loglik;
            lw[j] = lpn[j] - (double)logpi_K[src] + lvm - (double)logvp_KJ[z];
        }
        double m = fmax(fmax(lw[0], lw[1]), fmax(lw[2], lw[3]));
        double ssum = exp(lw[0] - m) + exp(lw[1] - m) + exp(lw[2] - m) + exp(lw[3] - m);
        double logw = m + log(ssum) - log((double)J_);
        int best = 0;
        double bv = lw[0] + (double)gumbel_KJ[k * J_ + 0];
        for (int j = 1; j < J_; ++j) {
            double v = lw[j] + (double)gumbel_KJ[k * J_ + j];
            if (v > bv) { bv = v; best = j; }
        }
        out[OFF_LPN + k] = (float)lpn[best];
        out[OFF_LW + k] = (float)logw;
        out[OFF_LL + k] = (float)llik[best];
        sub_idx[k] = best;
    }
}

// ---------- kernel 4: assemble all big outputs for the selected proposal ----------
__global__ __launch_bounds__(256) void k_output(
    const int* __restrict__ indexes, const int* __restrict__ m1_Kr,
    const int* __restrict__ m2_Kr, const float* __restrict__ b1_Kr,
    const float* __restrict__ b2_Kr, const float* __restrict__ embr,
    const int* __restrict__ lc_Kt, const int* __restrict__ h_Kt,
    const float* __restrict__ embt, const float* __restrict__ lf,
    const int* __restrict__ idx1_KJ, const int* __restrict__ idx2_KJ,
    const float* __restrict__ br1_KJ, const float* __restrict__ br2_KJ,
    const float* __restrict__ emb_KJD, const float* __restrict__ Wq,
    const int* __restrict__ sub_idx, float* __restrict__ out) {
    int blk = blockIdx.x;
    int k = blk >> 5, part = blk & 31;
    int tid = threadIdx.x;
    int src = indexes[k];
    int sub = sub_idx[k];
    int z = k * J_ + sub;
    int i1 = idx1_KJ[z], i2 = idx2_KJ[z];
    int mn = min(i1, i2), mx = max(i1, i2);

    if (part < 30) {
        // kept Felsenstein row t'=part  (src index with removed positions skipped)
        int st = part;
        if (st >= mn) ++st;
        if (st >= mx) ++st;
        const float4 v = *(const float4*)&lf[((size_t)(src * T_ + st) * S_ + tid) * A_];
        *(float4*)&out[OFF_LF + ((size_t)(k * 31 + part) * S_ + tid) * A_] = v;
    } else if (part == 30) {
        // new Felsenstein row
        __shared__ float s_logP1[16], s_logP2[16];
        if (tid == 0)
            compute_logP_pair(&emb_KJD[z * D_], Wq, br1_KJ[z], br2_KJ[z], s_logP1, s_logP2);
        __syncthreads();
        const float4 f1 = *(const float4*)&lf[((size_t)(src * T_ + i1) * S_ + tid) * A_];
        const float4 f2 = *(const float4*)&lf[((size_t)(src * T_ + i2) * S_ + tid) * A_];
        float4 o4;
        float nlf[4];
#pragma unroll
        for (int a = 0; a < 4; ++a) {
            float t1 = lse4f(s_logP1[a * 4 + 0] + f1.x, s_logP1[a * 4 + 1] + f1.y,
                             s_logP1[a * 4 + 2] + f1.z, s_logP1[a * 4 + 3] + f1.w);
            float t2 = lse4f(s_logP2[a * 4 + 0] + f2.x, s_logP2[a * 4 + 1] + f2.y,
                             s_logP2[a * 4 + 2] + f2.z, s_logP2[a * 4 + 3] + f2.w);
            nlf[a] = t1 + t2;
        }
        o4.x = nlf[0]; o4.y = nlf[1]; o4.z = nlf[2]; o4.w = nlf[3];
        *(float4*)&out[OFF_LF + ((size_t)(k * 31 + 30) * S_ + tid) * A_] = o4;
    } else {
        // part == 31: all small outputs for particle k
        for (int i = tid; i < 33; i += 256) {
            float v1, v2, fb1, fb2;
            if (i < 32) {
                v1 = (float)m1_Kr[src * R_ + i];
                v2 = (float)m2_Kr[src * R_ + i];
                fb1 = b1_Kr[src * R_ + i];
                fb2 = b2_Kr[src * R_ + i];
            } else {
                v1 = (float)i1; v2 = (float)i2;
                fb1 = br1_KJ[z]; fb2 = br2_KJ[z];
            }
            out[OFF_M1 + k * 33 + i] = v1;
            out[OFF_M2 + k * 33 + i] = v2;
            out[OFF_B1 + k * 33 + i] = fb1;
            out[OFF_B2 + k * 33 + i] = fb2;
        }
        for (int i = tid; i < 33 * D_; i += 256) {
            int r = i >> 6, d = i & 63;
            float v = (r < 32) ? embr[(src * R_ + r) * D_ + d] : emb_KJD[z * D_ + d];
            out[OFF_EMBR + k * 33 * D_ + i] = v;
        }
        for (int i = tid; i < 31; i += 256) {
            int lcv, hv;
            if (i < 30) {
                int st = i;
                if (st >= mn) ++st;
                if (st >= mx) ++st;
                lcv = lc_Kt[src * T_ + st];
                hv = h_Kt[src * T_ + st];
            } else {
                lcv = lc_Kt[src * T_ + i1] + lc_Kt[src * T_ + i2];
                int h1 = h_Kt[src * T_ + i1], h2 = h_Kt[src * T_ + i2];
                int hmn = min(h1, h2), hmx = max(h1, h2);
                unsigned int u = ((unsigned int)hmn * 1000003u + (unsigned int)hmx) * 40503u
                                 + 2531011u;
                hv = (int)u;  // int32 wraparound, matches JAX
            }
            out[OFF_LC + k * 31 + i] = (float)lcv;
            out[OFF_H + k * 31 + i] = (float)hv;
        }
        for (int i = tid; i < 31 * D_; i += 256) {
            int t = i >> 6, d = i & 63;
            float v;
            if (t < 30) {
                int st = t;
                if (st >= mn) ++st;
                if (st >= mx) ++st;
                v = embt[(src * T_ + st) * D_ + d];
            } else {
                v = emb_KJD[z * D_ + d];
            }
            out[OFF_EMBT + k * 31 * D_ + i] = v;
        }
    }
}

extern "C" void kernel_launch(void* const* d_in, const int* in_sizes, int n_in,
                              void* d_out, int out_size, void* d_ws, size_t ws_size,
                              hipStream_t stream) {
    const int* indexes   = (const int*)d_in[0];
    const int* m1_Kr     = (const int*)d_in[1];
    const int* m2_Kr     = (const int*)d_in[2];
    const float* b1_Kr   = (const float*)d_in[3];
    const float* b2_Kr   = (const float*)d_in[4];
    const float* embr    = (const float*)d_in[5];
    const int* lc_Kt     = (const int*)d_in[6];
    const int* h_Kt      = (const int*)d_in[7];
    const float* embt    = (const float*)d_in[8];
    const float* lf      = (const float*)d_in[9];
    const float* logpi_K = (const float*)d_in[10];
    const int* idx1_KJ   = (const int*)d_in[11];
    const int* idx2_KJ   = (const int*)d_in[12];
    const float* br1_KJ  = (const float*)d_in[13];
    const float* br2_KJ  = (const float*)d_in[14];
    const float* emb_KJD = (const float*)d_in[15];
    const float* logvp_KJ = (const float*)d_in[16];
    const float* gumbel_KJ = (const float*)d_in[17];
    const float* Wq      = (const float*)d_in[18];
    const float* Wstat   = (const float*)d_in[19];
    const float* ldf     = (const float*)d_in[20];

    float* out = (float*)d_out;
    float* ws_f = (float*)d_ws;
    float* new_node_ll = ws_f;                 // Z_ floats
    float* node_ll = ws_f + Z_;                // K_*T_ floats
    int* sub_idx = (int*)(ws_f + Z_ + K_ * T_); // K_ ints

    k_node_ll<<<K_ * T_, 256, 0, stream>>>(indexes, embt, Wstat, lf, node_ll);
    k_hyp<<<Z_, 256, 0, stream>>>(indexes, idx1_KJ, idx2_KJ, br1_KJ, br2_KJ, emb_KJD,
                                  Wq, Wstat, lf, new_node_ll);
    k_finalize<<<K_, 64, 0, stream>>>(indexes, lc_Kt, b1_Kr, b2_Kr, logpi_K, idx1_KJ,
                                      idx2_KJ, br1_KJ, br2_KJ, logvp_KJ, gumbel_KJ,
                                      ldf, node_ll, new_node_ll, out, sub_idx);
    k_output<<<K_ * 32, 256, 0, stream>>>(indexes, m1_Kr, m2_Kr, b1_Kr, b2_Kr, embr,
                                          lc_Kt, h_Kt, embt, lf, idx1_KJ, idx2_KJ,
                                          br1_KJ, br2_KJ, emb_KJD, Wq, sub_idx, out);
}

// Round 2
// 149.245 us; speedup vs baseline: 6.5488x; 6.5488x over previous
//
#include <hip/hip_runtime.h>
#include <math.h>

// Problem dims
constexpr int K_ = 128, J_ = 4, R_ = 32, T_ = 32, S_ = 256, A_ = 4, D_ = 64;
constexpr int Z_ = K_ * J_;
constexpr int NDF_ = 128;          // 2N
constexpr float RATE_ = 10.0f;     // 1/PRIOR_BL

// Output offsets (float elements) in return order
constexpr int OFF_M1   = 0;                       // K x 33 (int->float)
constexpr int OFF_M2   = OFF_M1 + K_ * 33;
constexpr int OFF_B1   = OFF_M2 + K_ * 33;
constexpr int OFF_B2   = OFF_B1 + K_ * 33;
constexpr int OFF_EMBR = OFF_B2 + K_ * 33;        // K x 33 x 64
constexpr int OFF_LC   = OFF_EMBR + K_ * 33 * D_; // K x 31
constexpr int OFF_H    = OFF_LC + K_ * 31;
constexpr int OFF_EMBT = OFF_H + K_ * 31;         // K x 31 x 64
constexpr int OFF_LF   = OFF_EMBT + K_ * 31 * D_; // K x 31 x 256 x 4
constexpr int OFF_LPN  = OFF_LF + K_ * 31 * S_ * A_;
constexpr int OFF_LW   = OFF_LPN + K_;
constexpr int OFF_LL   = OFF_LW + K_;

// ---------- device helpers ----------

__device__ inline float lse4f(float a, float b, float c, float d) {
    float m = fmaxf(fmaxf(a, b), fmaxf(c, d));
    return m + logf(expf(a - m) + expf(b - m) + expf(c - m) + expf(d - m));
}

// ---------- kernel 0: parallel 4x4 expm -> logP workspace ----------
// 32 threads per proposal z (16 for P1, 16 for P2), one thread per matrix
// element. Matrices in LDS (double). Fixed scaling 2^-6, Taylor-10, 6 squarings
// (uniform control flow, no norm-dependent branching).
__global__ __launch_bounds__(256) void k_expm(
    const float* __restrict__ br1_KJ, const float* __restrict__ br2_KJ,
    const float* __restrict__ emb_KJD, const float* __restrict__ Wq,
    float* __restrict__ logP_ws /* Z x 32 : [z][half][e] */) {
    int tid = threadIdx.x;
    int g = tid >> 5;           // group within block (one z per group)
    int q = tid & 31;
    int half = q >> 4;          // 0 => branch1, 1 => branch2
    int e = q & 15;
    int i = e >> 2, j = e & 3;
    int z = blockIdx.x * 8 + g;

    __shared__ double s_sp[8][16];       // softplus(logits), off-diag
    __shared__ double s_asc[8][2][16];   // scaled matrix
    __shared__ double s_term[8][2][16];  // Taylor term
    __shared__ double s_acc[8][2][16];   // accumulator / squaring

    // 1) Q logits (only half==0 computes; shared by both halves)
    if (half == 0) {
        const float* emb = &emb_KJD[z * D_];
        float lg = 0.f;
        for (int d = 0; d < D_; ++d) lg += emb[d] * Wq[d * 16 + e];
        double sp = 0.0;
        if (i != j) {
            double x = (double)lg;
            sp = (x > 30.0) ? x : log1p(exp(x));
        }
        s_sp[g][e] = sp;
    }
    __syncthreads();

    // 2) Q element, M = Q*br, Asc = M / 64
    double qv;
    if (i == j)
        qv = -(s_sp[g][i * 4 + 0] + s_sp[g][i * 4 + 1] +
               s_sp[g][i * 4 + 2] + s_sp[g][i * 4 + 3]);
    else
        qv = s_sp[g][e];
    double br = (double)(half == 0 ? br1_KJ[z] : br2_KJ[z]);
    double asc = qv * br * (1.0 / 64.0);
    s_asc[g][half][e] = asc;
    double ident = (i == j) ? 1.0 : 0.0;
    s_term[g][half][e] = ident;
    double accv = ident;
    __syncthreads();

    // 3) Taylor n=1..10 on the scaled matrix
    const double inv_n[11] = {0.0, 1.0, 0.5, 1.0 / 3.0, 0.25, 0.2,
                              1.0 / 6.0, 1.0 / 7.0, 0.125, 1.0 / 9.0, 0.1};
#pragma unroll
    for (int n = 1; n <= 10; ++n) {
        double t = (s_term[g][half][i * 4 + 0] * s_asc[g][half][0 * 4 + j] +
                    s_term[g][half][i * 4 + 1] * s_asc[g][half][1 * 4 + j] +
                    s_term[g][half][i * 4 + 2] * s_asc[g][half][2 * 4 + j] +
                    s_term[g][half][i * 4 + 3] * s_asc[g][half][3 * 4 + j]) *
                   inv_n[n];
        __syncthreads();
        s_term[g][half][e] = t;
        accv += t;
        __syncthreads();
    }

    // 4) 6 squarings
    s_acc[g][half][e] = accv;
    __syncthreads();
#pragma unroll
    for (int sq = 0; sq < 6; ++sq) {
        double t = s_acc[g][half][i * 4 + 0] * s_acc[g][half][0 * 4 + j] +
                   s_acc[g][half][i * 4 + 1] * s_acc[g][half][1 * 4 + j] +
                   s_acc[g][half][i * 4 + 2] * s_acc[g][half][2 * 4 + j] +
                   s_acc[g][half][i * 4 + 3] * s_acc[g][half][3 * 4 + j];
        __syncthreads();
        s_acc[g][half][e] = t;
        __syncthreads();
    }

    double p = s_acc[g][half][e];
    if (p < 1e-30) p = 1e-30;
    logP_ws[z * 32 + half * 16 + e] = (float)log(p);
}

// ---------- kernel 1: node_ll[k][t] = sum_s LSE_a(lf + log_stat_orig) ----------
__global__ __launch_bounds__(256) void k_node_ll(
    const int* __restrict__ indexes, const float* __restrict__ embt,
    const float* __restrict__ Wstat, const float* __restrict__ lf,
    float* __restrict__ node_ll) {
    int kt = blockIdx.x;
    int k = kt / T_, t = kt % T_;
    int src = indexes[k];
    int tid = threadIdx.x, wave = tid >> 6, lane = tid & 63;
    __shared__ float s_logit[4];
    __shared__ double s_part[4];
    {
        float e = embt[(src * T_ + t) * D_ + lane];
        float v = e * Wstat[lane * A_ + wave];
        for (int o = 32; o > 0; o >>= 1) v += __shfl_down(v, o, 64);
        if (lane == 0) s_logit[wave] = v;
    }
    __syncthreads();
    float l0 = s_logit[0], l1 = s_logit[1], l2 = s_logit[2], l3 = s_logit[3];
    float lse = lse4f(l0, l1, l2, l3);
    float ls0 = l0 - lse, ls1 = l1 - lse, ls2 = l2 - lse, ls3 = l3 - lse;
    const float4 f = *(const float4*)&lf[((size_t)(src * T_ + t) * S_ + tid) * A_];
    float site = lse4f(f.x + ls0, f.y + ls1, f.z + ls2, f.w + ls3);
    double v = (double)site;
    for (int o = 32; o > 0; o >>= 1) v += __shfl_down(v, o, 64);
    if (lane == 0) s_part[wave] = v;
    __syncthreads();
    if (tid == 0)
        node_ll[k * T_ + t] = (float)(s_part[0] + s_part[1] + s_part[2] + s_part[3]);
}

// ---------- kernel 2: per-proposal new-node log-lik ----------
__global__ __launch_bounds__(256) void k_hyp(
    const int* __restrict__ indexes, const int* __restrict__ idx1_KJ,
    const int* __restrict__ idx2_KJ, const float* __restrict__ emb_KJD,
    const float* __restrict__ Wstat, const float* __restrict__ lf,
    const float* __restrict__ logP_ws, float* __restrict__ new_node_ll) {
    int z = blockIdx.x;
    int k = z / J_;
    int src = indexes[k];
    int i1 = idx1_KJ[z], i2 = idx2_KJ[z];
    int tid = threadIdx.x, wave = tid >> 6, lane = tid & 63;
    __shared__ float s_logP[32], s_logit[4];
    __shared__ double s_part[4];
    {
        float e = emb_KJD[z * D_ + lane];
        float v = e * Wstat[lane * A_ + wave];
        for (int o = 32; o > 0; o >>= 1) v += __shfl_down(v, o, 64);
        if (lane == 0) s_logit[wave] = v;
    }
    if (tid < 32) s_logP[tid] = logP_ws[z * 32 + tid];
    __syncthreads();
    float l0 = s_logit[0], l1 = s_logit[1], l2 = s_logit[2], l3 = s_logit[3];
    float lse = lse4f(l0, l1, l2, l3);
    float ls[4] = {l0 - lse, l1 - lse, l2 - lse, l3 - lse};
    const float4 f1 = *(const float4*)&lf[((size_t)(src * T_ + i1) * S_ + tid) * A_];
    const float4 f2 = *(const float4*)&lf[((size_t)(src * T_ + i2) * S_ + tid) * A_];
    float nlf[4];
#pragma unroll
    for (int a = 0; a < 4; ++a) {
        float t1 = lse4f(s_logP[a * 4 + 0] + f1.x, s_logP[a * 4 + 1] + f1.y,
                         s_logP[a * 4 + 2] + f1.z, s_logP[a * 4 + 3] + f1.w);
        float t2 = lse4f(s_logP[16 + a * 4 + 0] + f2.x, s_logP[16 + a * 4 + 1] + f2.y,
                         s_logP[16 + a * 4 + 2] + f2.z, s_logP[16 + a * 4 + 3] + f2.w);
        nlf[a] = t1 + t2;
    }
    float site = lse4f(nlf[0] + ls[0], nlf[1] + ls[1], nlf[2] + ls[2], nlf[3] + ls[3]);
    double v = (double)site;
    for (int o = 32; o > 0; o >>= 1) v += __shfl_down(v, o, 64);
    if (lane == 0) s_part[wave] = v;
    __syncthreads();
    if (tid == 0)
        new_node_ll[z] = (float)(s_part[0] + s_part[1] + s_part[2] + s_part[3]);
}

// ---------- kernel 3: weights, selection, scalar outputs ----------
__global__ __launch_bounds__(64) void k_finalize(
    const int* __restrict__ indexes, const int* __restrict__ lc_Kt,
    const float* __restrict__ b1_Kr, const float* __restrict__ b2_Kr,
    const float* __restrict__ logpi_K, const int* __restrict__ idx1_KJ,
    const int* __restrict__ idx2_KJ, const float* __restrict__ br1_KJ,
    const float* __restrict__ br2_KJ, const float* __restrict__ logvp_KJ,
    const float* __restrict__ gumbel_KJ, const float* __restrict__ ldf,
    const float* __restrict__ node_ll, const float* __restrict__ new_node_ll,
    float* __restrict__ out, int* __restrict__ sub_idx) {
    int k = blockIdx.x;
    int lane = threadIdx.x;
    int src = indexes[k];
    double nll = 0.0, topo = 0.0, sb1 = 0.0, sb2 = 0.0;
    int cnt = 0;
    if (lane < T_) {
        nll = (double)node_ll[k * T_ + lane];
        int lc = lc_Kt[src * T_ + lane];
        int di = 2 * lc - 3; di = max(0, min(NDF_ - 1, di));
        topo = (double)ldf[di];
        cnt = (lc > 1) ? 1 : 0;
        sb1 = (double)b1_Kr[src * R_ + lane];
        sb2 = (double)b2_Kr[src * R_ + lane];
    }
    for (int o = 32; o > 0; o >>= 1) {
        nll += __shfl_down(nll, o, 64);
        topo += __shfl_down(topo, o, 64);
        sb1 += __shfl_down(sb1, o, 64);
        sb2 += __shfl_down(sb2, o, 64);
        cnt += __shfl_down(cnt, o, 64);
    }
    if (lane == 0) {
        double total_ll = nll, base_topo = -topo;
        const double lr = log(10.0);
        double lw[4], lpn[4], llik[4];
        for (int j = 0; j < J_; ++j) {
            int z = k * J_ + j;
            int i1 = idx1_KJ[z], i2 = idx2_KJ[z];
            int lc1 = lc_Kt[src * T_ + i1], lc2 = lc_Kt[src * T_ + i2];
            int nlc = lc1 + lc2;
            double loglik = total_ll - (double)node_ll[k * T_ + i1]
                                     - (double)node_ll[k * T_ + i2]
                                     + (double)new_node_ll[z];
            double lbp = 66.0 * lr
                       - (double)RATE_ * (sb1 + (double)br1_KJ[z] + sb2 + (double)br2_KJ[z]);
            int d1 = max(0, min(NDF_ - 1, 2 * lc1 - 3));
            int d2 = max(0, min(NDF_ - 1, 2 * lc2 - 3));
            int dn = max(0, min(NDF_ - 1, 2 * nlc - 3));
            double lt = base_topo + (double)ldf[d1] + (double)ldf[d2] - (double)ldf[dn];
            int cntj = cnt - ((lc1 > 1) ? 1 : 0) - ((lc2 > 1) ? 1 : 0) + 1;
            double lvm = log((double)cntj);
            lpn[j] = loglik + lbp + lt;
            llik[j] = loglik;
            lw[j] = lpn[j] - (double)logpi_K[src] + lvm - (double)logvp_KJ[z];
        }
        double m = fmax(fmax(lw[0], lw[1]), fmax(lw[2], lw[3]));
        double ssum = exp(lw[0] - m) + exp(lw[1] - m) + exp(lw[2] - m) + exp(lw[3] - m);
        double logw = m + log(ssum) - log((double)J_);
        int best = 0;
        double bv = lw[0] + (double)gumbel_KJ[k * J_ + 0];
        for (int j = 1; j < J_; ++j) {
            double v = lw[j] + (double)gumbel_KJ[k * J_ + j];
            if (v > bv) { bv = v; best = j; }
        }
        out[OFF_LPN + k] = (float)lpn[best];
        out[OFF_LW + k] = (float)logw;
        out[OFF_LL + k] = (float)llik[best];
        sub_idx[k] = best;
    }
}

// ---------- kernel 4: assemble all big outputs for the selected proposal ----------
__global__ __launch_bounds__(256) void k_output(
    const int* __restrict__ indexes, const int* __restrict__ m1_Kr,
    const int* __restrict__ m2_Kr, const float* __restrict__ b1_Kr,
    const float* __restrict__ b2_Kr, const float* __restrict__ embr,
    const int* __restrict__ lc_Kt, const int* __restrict__ h_Kt,
    const float* __restrict__ embt, const float* __restrict__ lf,
    const int* __restrict__ idx1_KJ, const int* __restrict__ idx2_KJ,
    const float* __restrict__ br1_KJ, const float* __restrict__ br2_KJ,
    const float* __restrict__ emb_KJD, const float* __restrict__ logP_ws,
    const int* __restrict__ sub_idx, float* __restrict__ out) {
    int blk = blockIdx.x;
    int k = blk >> 5, part = blk & 31;
    int tid = threadIdx.x;
    int src = indexes[k];
    int sub = sub_idx[k];
    int z = k * J_ + sub;
    int i1 = idx1_KJ[z], i2 = idx2_KJ[z];
    int mn = min(i1, i2), mx = max(i1, i2);

    if (part < 30) {
        int st = part;
        if (st >= mn) ++st;
        if (st >= mx) ++st;
        const float4 v = *(const float4*)&lf[((size_t)(src * T_ + st) * S_ + tid) * A_];
        *(float4*)&out[OFF_LF + ((size_t)(k * 31 + part) * S_ + tid) * A_] = v;
    } else if (part == 30) {
        __shared__ float s_logP[32];
        if (tid < 32) s_logP[tid] = logP_ws[z * 32 + tid];
        __syncthreads();
        const float4 f1 = *(const float4*)&lf[((size_t)(src * T_ + i1) * S_ + tid) * A_];
        const float4 f2 = *(const float4*)&lf[((size_t)(src * T_ + i2) * S_ + tid) * A_];
        float4 o4;
        float nlf[4];
#pragma unroll
        for (int a = 0; a < 4; ++a) {
            float t1 = lse4f(s_logP[a * 4 + 0] + f1.x, s_logP[a * 4 + 1] + f1.y,
                             s_logP[a * 4 + 2] + f1.z, s_logP[a * 4 + 3] + f1.w);
            float t2 = lse4f(s_logP[16 + a * 4 + 0] + f2.x, s_logP[16 + a * 4 + 1] + f2.y,
                             s_logP[16 + a * 4 + 2] + f2.z, s_logP[16 + a * 4 + 3] + f2.w);
            nlf[a] = t1 + t2;
        }
        o4.x = nlf[0]; o4.y = nlf[1]; o4.z = nlf[2]; o4.w = nlf[3];
        *(float4*)&out[OFF_LF + ((size_t)(k * 31 + 30) * S_ + tid) * A_] = o4;
    } else {
        // part == 31: all small outputs for particle k
        for (int i = tid; i < 33; i += 256) {
            float v1, v2, fb1, fb2;
            if (i < 32) {
                v1 = (float)m1_Kr[src * R_ + i];
                v2 = (float)m2_Kr[src * R_ + i];
                fb1 = b1_Kr[src * R_ + i];
                fb2 = b2_Kr[src * R_ + i];
            } else {
                v1 = (float)i1; v2 = (float)i2;
                fb1 = br1_KJ[z]; fb2 = br2_KJ[z];
            }
            out[OFF_M1 + k * 33 + i] = v1;
            out[OFF_M2 + k * 33 + i] = v2;
            out[OFF_B1 + k * 33 + i] = fb1;
            out[OFF_B2 + k * 33 + i] = fb2;
        }
        for (int i = tid; i < 33 * D_; i += 256) {
            int r = i >> 6, d = i & 63;
            float v = (r < 32) ? embr[(src * R_ + r) * D_ + d] : emb_KJD[z * D_ + d];
            out[OFF_EMBR + k * 33 * D_ + i] = v;
        }
        for (int i = tid; i < 31; i += 256) {
            int lcv, hv;
            if (i < 30) {
                int st = i;
                if (st >= mn) ++st;
                if (st >= mx) ++st;
                lcv = lc_Kt[src * T_ + st];
                hv = h_Kt[src * T_ + st];
            } else {
                lcv = lc_Kt[src * T_ + i1] + lc_Kt[src * T_ + i2];
                int h1 = h_Kt[src * T_ + i1], h2 = h_Kt[src * T_ + i2];
                int hmn = min(h1, h2), hmx = max(h1, h2);
                unsigned int u = ((unsigned int)hmn * 1000003u + (unsigned int)hmx) * 40503u
                                 + 2531011u;
                hv = (int)u;  // int32 wraparound, matches JAX
            }
            out[OFF_LC + k * 31 + i] = (float)lcv;
            out[OFF_H + k * 31 + i] = (float)hv;
        }
        for (int i = tid; i < 31 * D_; i += 256) {
            int t = i >> 6, d = i & 63;
            float v;
            if (t < 30) {
                int st = t;
                if (st >= mn) ++st;
                if (st >= mx) ++st;
                v = embt[(src * T_ + st) * D_ + d];
            } else {
                v = emb_KJD[z * D_ + d];
            }
            out[OFF_EMBT + k * 31 * D_ + i] = v;
        }
    }
}

extern "C" void kernel_launch(void* const* d_in, const int* in_sizes, int n_in,
                              void* d_out, int out_size, void* d_ws, size_t ws_size,
                              hipStream_t stream) {
    const int* indexes   = (const int*)d_in[0];
    const int* m1_Kr     = (const int*)d_in[1];
    const int* m2_Kr     = (const int*)d_in[2];
    const float* b1_Kr   = (const float*)d_in[3];
    const float* b2_Kr   = (const float*)d_in[4];
    const float* embr    = (const float*)d_in[5];
    const int* lc_Kt     = (const int*)d_in[6];
    const int* h_Kt      = (const int*)d_in[7];
    const float* embt    = (const float*)d_in[8];
    const float* lf      = (const float*)d_in[9];
    const float* logpi_K = (const float*)d_in[10];
    const int* idx1_KJ   = (const int*)d_in[11];
    const int* idx2_KJ   = (const int*)d_in[12];
    const float* br1_KJ  = (const float*)d_in[13];
    const float* br2_KJ  = (const float*)d_in[14];
    const float* emb_KJD = (const float*)d_in[15];
    const float* logvp_KJ = (const float*)d_in[16];
    const float* gumbel_KJ = (const float*)d_in[17];
    const float* Wq      = (const float*)d_in[18];
    const float* Wstat   = (const float*)d_in[19];
    const float* ldf     = (const float*)d_in[20];

    float* out = (float*)d_out;
    float* ws_f = (float*)d_ws;
    float* new_node_ll = ws_f;                          // Z_
    float* node_ll = ws_f + Z_;                         // K_*T_
    int* sub_idx = (int*)(ws_f + Z_ + K_ * T_);         // K_ ints
    float* logP_ws = ws_f + Z_ + K_ * T_ + K_;          // Z_*32

    k_expm<<<Z_ / 8, 256, 0, stream>>>(br1_KJ, br2_KJ, emb_KJD, Wq, logP_ws);
    k_node_ll<<<K_ * T_, 256, 0, stream>>>(indexes, embt, Wstat, lf, node_ll);
    k_hyp<<<Z_, 256, 0, stream>>>(indexes, idx1_KJ, idx2_KJ, emb_KJD, Wstat, lf,
                                  logP_ws, new_node_ll);
    k_finalize<<<K_, 64, 0, stream>>>(indexes, lc_Kt, b1_Kr, b2_Kr, logpi_K, idx1_KJ,
                                      idx2_KJ, br1_KJ, br2_KJ, logvp_KJ, gumbel_KJ,
                                      ldf, node_ll, new_node_ll, out, sub_idx);
    k_output<<<K_ * 32, 256, 0, stream>>>(indexes, m1_Kr, m2_Kr, b1_Kr, b2_Kr, embr,
                                          lc_Kt, h_Kt, embt, lf, idx1_KJ, idx2_KJ,
                                          br1_KJ, br2_KJ, emb_KJD, logP_ws, sub_idx, out);
}